// Round 7
// baseline (261.768 us; speedup 1.0000x reference)
//
#include <hip/hip_runtime.h>
#include <hip/hip_bf16.h>

#define IN_F 8192
#define OUT_F 8192
#define SEQ 64
#define LORA_R 16

typedef __attribute__((ext_vector_type(4))) float f32x4;
typedef __attribute__((ext_vector_type(4))) int i32x4;
typedef __attribute__((ext_vector_type(8))) unsigned short u16x8;
typedef _Float16 f16x2 __attribute__((ext_vector_type(2)));
typedef _Float16 f16x8 __attribute__((ext_vector_type(8)));

// ============ prep: x_sw (fragment-ordered fp16 x), sc_sw, zero out, t = x@A^T ============
// grid 1856 x 256:
//   [0,256)     x_sw: thread -> one 16B granule g = ((kstep*4+mt)*4+q)*16+c16
//   [256,768)   zero out (2 MB)
//   [768,1792)  sc_sw: 4 entries/thread; entry e = ((ntile*128+kblk)*2+nh)*16+c16
//   [1792,1856) t rows (one block per s)
__global__ __launch_bounds__(256) void k_prep(
    const float* __restrict__ x, const float* __restrict__ A,
    const float* __restrict__ scales,
    unsigned short* __restrict__ x_sw, float* __restrict__ sc_sw,
    float* __restrict__ t, float* __restrict__ out) {
    const int bid = blockIdx.x, tid = threadIdx.x;
    if (bid < 256) {
        int g = bid * 256 + tid;
        int c16 = g & 15, q = (g >> 4) & 3, mt = (g >> 6) & 3, kstep = g >> 8;
        int row = mt * 16 + c16, k0 = kstep * 32 + q * 8;
        const float* src = x + row * IN_F + k0;
        f32x4 v0 = *(const f32x4*)src;
        f32x4 v1 = *(const f32x4*)(src + 4);
        u16x8 h;
        h[0] = __builtin_bit_cast(unsigned short, (_Float16)v0.x);
        h[1] = __builtin_bit_cast(unsigned short, (_Float16)v0.y);
        h[2] = __builtin_bit_cast(unsigned short, (_Float16)v0.z);
        h[3] = __builtin_bit_cast(unsigned short, (_Float16)v0.w);
        h[4] = __builtin_bit_cast(unsigned short, (_Float16)v1.x);
        h[5] = __builtin_bit_cast(unsigned short, (_Float16)v1.y);
        h[6] = __builtin_bit_cast(unsigned short, (_Float16)v1.z);
        h[7] = __builtin_bit_cast(unsigned short, (_Float16)v1.w);
        *(u16x8*)(x_sw + g * 8) = h;
    } else if (bid < 768) {
        int i = (bid - 256) * 256 + tid;
        *(f32x4*)(out + i * 4) = (f32x4){0.f, 0.f, 0.f, 0.f};
    } else if (bid < 1792) {
        int e0 = ((bid - 768) * 256 + tid) * 4;
        int c16 = e0 & 15, nh = (e0 >> 4) & 1, kblk = (e0 >> 5) & 127, ntile = e0 >> 12;
        int rowb = ntile * 32 + nh * 16 + c16;
        f32x4 v;
        v.x = scales[(rowb + 0) * 128 + kblk];
        v.y = scales[(rowb + 1) * 128 + kblk];
        v.z = scales[(rowb + 2) * 128 + kblk];
        v.w = scales[(rowb + 3) * 128 + kblk];
        *(f32x4*)(sc_sw + e0) = v;
    } else {
        __shared__ float p[LORA_R][17];
        const int s = bid - 1792;
        const int r = tid & 15, seg = tid >> 4;   // 16 segs x 512 cols
        const float* xr = x + s * IN_F + seg * 512;
        const float* ar = A + r * IN_F + seg * 512;
        float acc = 0.f;
        #pragma unroll 8
        for (int j = 0; j < 128; ++j) {
            f32x4 xv = *(const f32x4*)(xr + j * 4);
            f32x4 av = *(const f32x4*)(ar + j * 4);
            acc = fmaf(xv.x, av.x, acc);
            acc = fmaf(xv.y, av.y, acc);
            acc = fmaf(xv.z, av.z, acc);
            acc = fmaf(xv.w, av.w, acc);
        }
        p[r][seg] = acc;
        __syncthreads();
        if (tid < LORA_R) {
            float sum = 0.f;
            #pragma unroll
            for (int g = 0; g < 16; ++g) sum += p[tid][g];
            t[s * LORA_R + tid] = sum;
        }
    }
}

// ============ main: BARRIER-FREE K-loop, direct per-lane loads, reg prefetch d=2 ============
// grid 1024 = 256 ntiles x 4 K-quarters; 256 thr = 4 waves (k-slices of 512).
// Per k-step per wave: 4 x_sw loads (1KB contiguous each), 2 W i32x4 loads, 2 scale loads,
// dequant (fp16 magic), 8 MFMAs (2 n-halves x 4 m-tiles). NO LDS/barriers in loop.
__global__ __launch_bounds__(256, 4) void k_main(
    const int* __restrict__ packed, const unsigned short* __restrict__ x_sw,
    const float* __restrict__ sc_sw, const float* __restrict__ t,
    const float* __restrict__ B, float* __restrict__ out) {
    __shared__ float accs[4][64][33];   // 33792 B

    const int tid = threadIdx.x;
    const int ntile = blockIdx.x >> 2, kq = blockIdx.x & 3;
    const int w = tid >> 6, lane = tid & 63;
    const int q = lane >> 4, c16 = lane & 15;
    const int ksg0 = kq * 64 + w * 16;            // global kstep base (16 steps of 32)

    // x_sw: halves offset = (((kstep*4+mt)*4+q)*16+c16)*8 ; strides: kstep 2048, mt 512
    const unsigned short* xp = x_sw + ((ksg0 * 16 + q) * 16 + c16) * 8;
    // W: int32 index = row*4096 + kstep*16 + q*4 ; nh stride 16*4096
    const int* wp = packed + (ntile * 32 + c16) * 4096 + ksg0 * 16 + q * 4;
    // sc_sw entry = ((ntile*128+kblk)*2+nh)*16 + c16
    const float* scp = sc_sw + (ntile * 128) * 32 + c16;

    f32x4 acc[8];
    #pragma unroll
    for (int i = 0; i < 8; ++i) acc[i] = (f32x4){0.f, 0.f, 0.f, 0.f};

    f16x8 xf[2][4];
    i32x4 wv[2][2];
    float sc[2][2];

    auto loadstep = [&](int s, int set) {
        #pragma unroll
        for (int mt = 0; mt < 4; ++mt)
            xf[set][mt] = *(const f16x8*)(xp + s * 2048 + mt * 512);
        wv[set][0] = *(const i32x4*)(wp + s * 16);
        wv[set][1] = *(const i32x4*)(wp + 16 * 4096 + s * 16);
        int kb = (ksg0 + s) >> 1;
        sc[set][0] = scp[(kb * 2 + 0) * 16];
        sc[set][1] = scp[(kb * 2 + 1) * 16];
    };

    loadstep(0, 0);
    loadstep(1, 1);

    const f16x2 c1032 = {(_Float16)1032.0f, (_Float16)1032.0f};

    #pragma unroll
    for (int s = 0; s < 16; ++s) {
        const int cur = s & 1;
        f16x8 a0 = xf[cur][0], a1 = xf[cur][1], a2 = xf[cur][2], a3 = xf[cur][3];
        i32x4 w0 = wv[cur][0], w1 = wv[cur][1];
        float s0 = sc[cur][0], s1 = sc[cur][1];
        if (s + 2 < 16) loadstep(s + 2, cur);

        #pragma unroll
        for (int nh = 0; nh < 2; ++nh) {
            i32x4 pv = nh ? w1 : w0;
            _Float16 sch = (_Float16)(nh ? s1 : s0);
            f16x2 sc2 = {sch, sch};
            f16x8 bf;
            #pragma unroll
            for (int m = 0; m < 4; ++m) {
                unsigned u = ((((unsigned)pv[m] << 12) | (unsigned)pv[m]) & 0x000F000Fu) | 0x64006400u;
                f16x2 hh = __builtin_bit_cast(f16x2, u);
                hh = (hh - c1032) * sc2;        // exact (q-8)*scale
                bf[2 * m] = hh.x;
                bf[2 * m + 1] = hh.y;
            }
            acc[nh * 4 + 0] = __builtin_amdgcn_mfma_f32_16x16x32_f16(a0, bf, acc[nh * 4 + 0], 0, 0, 0);
            acc[nh * 4 + 1] = __builtin_amdgcn_mfma_f32_16x16x32_f16(a1, bf, acc[nh * 4 + 1], 0, 0, 0);
            acc[nh * 4 + 2] = __builtin_amdgcn_mfma_f32_16x16x32_f16(a2, bf, acc[nh * 4 + 2], 0, 0, 0);
            acc[nh * 4 + 3] = __builtin_amdgcn_mfma_f32_16x16x32_f16(a3, bf, acc[nh * 4 + 3], 0, 0, 0);
        }
    }

    // ---- epilogue: cross-wave reduce in LDS + LoRA (kq==0) + atomic out ----
    #pragma unroll
    for (int nh = 0; nh < 2; ++nh)
        #pragma unroll
        for (int mt = 0; mt < 4; ++mt)
            #pragma unroll
            for (int r = 0; r < 4; ++r)
                accs[w][mt * 16 + q * 4 + r][nh * 16 + c16] = acc[nh * 4 + mt][r];
    __syncthreads();

    #pragma unroll
    for (int j = 0; j < 8; ++j) {
        int p = tid + j * 256;                    // 2048 outputs: s 0..63, c 0..31
        int s = p >> 5, c = p & 31;
        float v = accs[0][s][c] + accs[1][s][c] + accs[2][s][c] + accs[3][s][c];
        if (kq == 0) {
            const float* tp = t + s * LORA_R;
            const float* bp = B + (ntile * 32 + c) * LORA_R;
            float lr = 0.f;
            #pragma unroll
            for (int r = 0; r < LORA_R; ++r) lr = fmaf(tp[r], bp[r], lr);
            v += 2.0f * lr;
        }
        unsafeAtomicAdd(&out[s * OUT_F + ntile * 32 + c], v);
    }
}

extern "C" void kernel_launch(void* const* d_in, const int* in_sizes, int n_in,
                              void* d_out, int out_size, void* d_ws, size_t ws_size,
                              hipStream_t stream) {
    const float* x      = (const float*)d_in[0];
    const int* packed   = (const int*)d_in[1];
    const float* scales = (const float*)d_in[2];
    const float* lora_A = (const float*)d_in[3];
    const float* lora_B = (const float*)d_in[4];
    float* out = (float*)d_out;

    unsigned short* x_sw = (unsigned short*)d_ws;                       // 1 MiB
    float* sc_sw = (float*)((char*)d_ws + (size_t)SEQ * IN_F * 2);      // 4 MiB
    float* t = (float*)((char*)d_ws + (size_t)SEQ * IN_F * 2 + (size_t)OUT_F * 128 * 4);

    k_prep<<<1856, 256, 0, stream>>>(x, lora_A, scales, x_sw, sc_sw, t, out);
    k_main<<<1024, 256, 0, stream>>>(packed, x_sw, sc_sw, t, lora_B, out);
}

// Round 8
// 257.382 us; speedup vs baseline: 1.0170x; 1.0170x over previous
//
#include <hip/hip_runtime.h>
#include <hip/hip_bf16.h>

#define IN_F 8192
#define OUT_F 8192
#define SEQ 64
#define LORA_R 16

typedef __attribute__((ext_vector_type(4))) float f32x4;
typedef __attribute__((ext_vector_type(4))) int i32x4;
typedef __attribute__((ext_vector_type(8))) unsigned short u16x8;
typedef _Float16 f16x2 __attribute__((ext_vector_type(2)));
typedef _Float16 f16x8 __attribute__((ext_vector_type(8)));

// ============ prep: x_sw (fragment-ordered fp16 x), sc_sw, zero out, t = x@A^T ============
// grid 1856 x 256:
//   [0,256)     x_sw: thread -> one 16B granule g = ((kstep*4+mt)*4+q)*16+c16
//   [256,768)   zero out (2 MB)
//   [768,1792)  sc_sw: 4 entries/thread; entry e = ((ntile*128+kblk)*2+nh)*16+c16
//   [1792,1856) t rows (one block per s)
__global__ __launch_bounds__(256) void k_prep(
    const float* __restrict__ x, const float* __restrict__ A,
    const float* __restrict__ scales,
    unsigned short* __restrict__ x_sw, float* __restrict__ sc_sw,
    float* __restrict__ t, float* __restrict__ out) {
    const int bid = blockIdx.x, tid = threadIdx.x;
    if (bid < 256) {
        int g = bid * 256 + tid;
        int c16 = g & 15, q = (g >> 4) & 3, mt = (g >> 6) & 3, kstep = g >> 8;
        int row = mt * 16 + c16, k0 = kstep * 32 + q * 8;
        const float* src = x + row * IN_F + k0;
        f32x4 v0 = *(const f32x4*)src;
        f32x4 v1 = *(const f32x4*)(src + 4);
        u16x8 h;
        h[0] = __builtin_bit_cast(unsigned short, (_Float16)v0.x);
        h[1] = __builtin_bit_cast(unsigned short, (_Float16)v0.y);
        h[2] = __builtin_bit_cast(unsigned short, (_Float16)v0.z);
        h[3] = __builtin_bit_cast(unsigned short, (_Float16)v0.w);
        h[4] = __builtin_bit_cast(unsigned short, (_Float16)v1.x);
        h[5] = __builtin_bit_cast(unsigned short, (_Float16)v1.y);
        h[6] = __builtin_bit_cast(unsigned short, (_Float16)v1.z);
        h[7] = __builtin_bit_cast(unsigned short, (_Float16)v1.w);
        *(u16x8*)(x_sw + g * 8) = h;
    } else if (bid < 768) {
        int i = (bid - 256) * 256 + tid;
        *(f32x4*)(out + i * 4) = (f32x4){0.f, 0.f, 0.f, 0.f};
    } else if (bid < 1792) {
        int e0 = ((bid - 768) * 256 + tid) * 4;
        int c16 = e0 & 15, nh = (e0 >> 4) & 1, kblk = (e0 >> 5) & 127, ntile = e0 >> 12;
        int rowb = ntile * 32 + nh * 16 + c16;
        f32x4 v;
        v.x = scales[(rowb + 0) * 128 + kblk];
        v.y = scales[(rowb + 1) * 128 + kblk];
        v.z = scales[(rowb + 2) * 128 + kblk];
        v.w = scales[(rowb + 3) * 128 + kblk];
        *(f32x4*)(sc_sw + e0) = v;
    } else {
        __shared__ float p[LORA_R][17];
        const int s = bid - 1792;
        const int r = tid & 15, seg = tid >> 4;   // 16 segs x 512 cols
        const float* xr = x + s * IN_F + seg * 512;
        const float* ar = A + r * IN_F + seg * 512;
        float acc = 0.f;
        #pragma unroll 8
        for (int j = 0; j < 128; ++j) {
            f32x4 xv = *(const f32x4*)(xr + j * 4);
            f32x4 av = *(const f32x4*)(ar + j * 4);
            acc = fmaf(xv.x, av.x, acc);
            acc = fmaf(xv.y, av.y, acc);
            acc = fmaf(xv.z, av.z, acc);
            acc = fmaf(xv.w, av.w, acc);
        }
        p[r][seg] = acc;
        __syncthreads();
        if (tid < LORA_R) {
            float sum = 0.f;
            #pragma unroll
            for (int g = 0; g < 16; ++g) sum += p[tid][g];
            t[s * LORA_R + tid] = sum;
        }
    }
}

// ============ main: BARRIER-FREE K-loop, direct per-lane loads, reg prefetch d=2 ============
// grid 512 = 256 ntiles x 2 K-halves; 256 thr = 4 waves (k-slices of 1024 = 32 steps).
// launch_bounds(256,3): 170-VGPR budget -> no spill (R7's regression cause).
__global__ __launch_bounds__(256, 3) void k_main(
    const int* __restrict__ packed, const unsigned short* __restrict__ x_sw,
    const float* __restrict__ sc_sw, const float* __restrict__ t,
    const float* __restrict__ B, float* __restrict__ out) {
    __shared__ float accs[4][64][33];   // 33792 B (epilogue only)

    const int tid = threadIdx.x;
    const int ntile = blockIdx.x >> 1, kq = blockIdx.x & 1;
    const int w = tid >> 6, lane = tid & 63;
    const int q = lane >> 4, c16 = lane & 15;
    const int ksg0 = kq * 128 + w * 32;           // global kstep base (32 steps of 32)

    // x_sw: shorts offset = ((kstep*16+q)*16+c16)*8 ; kstep stride 2048 shorts, mt stride 512
    const unsigned short* xp = x_sw + ((ksg0 * 16 + q) * 16 + c16) * 8;
    // W: int32 index = row*4096 + kstep*16 + q*4 ; nh stride 16*4096
    const int* wp = packed + (ntile * 32 + c16) * 4096 + ksg0 * 16 + q * 4;
    // sc_sw entry = ntile*4096 + (kblk*2+nh)*16 + c16
    const float* scp = sc_sw + ntile * 4096 + c16;

    f32x4 acc[8];
    #pragma unroll
    for (int i = 0; i < 8; ++i) acc[i] = (f32x4){0.f, 0.f, 0.f, 0.f};

    f16x8 xf[2][4];
    i32x4 wv[2][2];
    float sc[2][2];

    auto loadstep = [&](int s, int set) {
        #pragma unroll
        for (int mt = 0; mt < 4; ++mt)
            xf[set][mt] = *(const f16x8*)(xp + s * 2048 + mt * 512);
        wv[set][0] = *(const i32x4*)(wp + s * 16);
        wv[set][1] = *(const i32x4*)(wp + 16 * 4096 + s * 16);
        int kb = (ksg0 + s) >> 1;
        sc[set][0] = scp[(kb * 2 + 0) * 16];
        sc[set][1] = scp[(kb * 2 + 1) * 16];
    };

    loadstep(0, 0);
    loadstep(1, 1);

    const f16x2 c1032 = {(_Float16)1032.0f, (_Float16)1032.0f};

    #pragma unroll 2
    for (int s = 0; s < 32; ++s) {
        const int cur = s & 1;
        f16x8 a0 = xf[cur][0], a1 = xf[cur][1], a2 = xf[cur][2], a3 = xf[cur][3];
        i32x4 w0 = wv[cur][0], w1 = wv[cur][1];
        float s0 = sc[cur][0], s1 = sc[cur][1];
        if (s + 2 < 32) loadstep(s + 2, cur);

        #pragma unroll
        for (int nh = 0; nh < 2; ++nh) {
            i32x4 pv = nh ? w1 : w0;
            _Float16 sch = (_Float16)(nh ? s1 : s0);
            f16x2 sc2 = {sch, sch};
            f16x8 bf;
            #pragma unroll
            for (int m = 0; m < 4; ++m) {
                unsigned u = ((((unsigned)pv[m] << 12) | (unsigned)pv[m]) & 0x000F000Fu) | 0x64006400u;
                f16x2 hh = __builtin_bit_cast(f16x2, u);
                hh = (hh - c1032) * sc2;        // exact (q-8)*scale
                bf[2 * m] = hh.x;
                bf[2 * m + 1] = hh.y;
            }
            acc[nh * 4 + 0] = __builtin_amdgcn_mfma_f32_16x16x32_f16(a0, bf, acc[nh * 4 + 0], 0, 0, 0);
            acc[nh * 4 + 1] = __builtin_amdgcn_mfma_f32_16x16x32_f16(a1, bf, acc[nh * 4 + 1], 0, 0, 0);
            acc[nh * 4 + 2] = __builtin_amdgcn_mfma_f32_16x16x32_f16(a2, bf, acc[nh * 4 + 2], 0, 0, 0);
            acc[nh * 4 + 3] = __builtin_amdgcn_mfma_f32_16x16x32_f16(a3, bf, acc[nh * 4 + 3], 0, 0, 0);
        }
    }

    // ---- epilogue: cross-wave reduce in LDS + LoRA (kq==0) + atomic out ----
    #pragma unroll
    for (int nh = 0; nh < 2; ++nh)
        #pragma unroll
        for (int mt = 0; mt < 4; ++mt)
            #pragma unroll
            for (int r = 0; r < 4; ++r)
                accs[w][mt * 16 + q * 4 + r][nh * 16 + c16] = acc[nh * 4 + mt][r];
    __syncthreads();

    #pragma unroll
    for (int j = 0; j < 8; ++j) {
        int p = tid + j * 256;                    // 2048 outputs: s 0..63, c 0..31
        int s = p >> 5, c = p & 31;
        float v = accs[0][s][c] + accs[1][s][c] + accs[2][s][c] + accs[3][s][c];
        if (kq == 0) {
            const float* tp = t + s * LORA_R;
            const float* bp = B + (ntile * 32 + c) * LORA_R;
            float lr = 0.f;
            #pragma unroll
            for (int r = 0; r < LORA_R; ++r) lr = fmaf(tp[r], bp[r], lr);
            v += 2.0f * lr;
        }
        unsafeAtomicAdd(&out[s * OUT_F + ntile * 32 + c], v);
    }
}

extern "C" void kernel_launch(void* const* d_in, const int* in_sizes, int n_in,
                              void* d_out, int out_size, void* d_ws, size_t ws_size,
                              hipStream_t stream) {
    const float* x      = (const float*)d_in[0];
    const int* packed   = (const int*)d_in[1];
    const float* scales = (const float*)d_in[2];
    const float* lora_A = (const float*)d_in[3];
    const float* lora_B = (const float*)d_in[4];
    float* out = (float*)d_out;

    unsigned short* x_sw = (unsigned short*)d_ws;                       // 1 MiB
    float* sc_sw = (float*)((char*)d_ws + (size_t)SEQ * IN_F * 2);      // 4 MiB
    float* t = (float*)((char*)d_ws + (size_t)SEQ * IN_F * 2 + (size_t)OUT_F * 128 * 4);

    k_prep<<<1856, 256, 0, stream>>>(x, lora_A, scales, x_sw, sc_sw, t, out);
    k_main<<<512, 256, 0, stream>>>(packed, x_sw, sc_sw, t, lora_B, out);
}

// Round 9
// 246.062 us; speedup vs baseline: 1.0638x; 1.0460x over previous
//
#include <hip/hip_runtime.h>
#include <hip/hip_bf16.h>

#define IN_F 8192
#define OUT_F 8192
#define SEQ 64
#define LORA_R 16

typedef __attribute__((ext_vector_type(4))) float f32x4;
typedef __attribute__((ext_vector_type(4))) int i32x4;
typedef __attribute__((ext_vector_type(8))) unsigned short u16x8;
typedef __attribute__((ext_vector_type(4))) unsigned short u16x4;
typedef _Float16 f16x2 __attribute__((ext_vector_type(2)));
typedef _Float16 f16x8 __attribute__((ext_vector_type(8)));

// ---- fused prep: zero out, cast x->fp16 into ws, and (blocks 0..63) t = x@A^T ----
__global__ __launch_bounds__(512) void k_prep(
    const float* __restrict__ x, const float* __restrict__ A,
    unsigned short* __restrict__ xb, float* __restrict__ t,
    float* __restrict__ out) {
    const int tid = threadIdx.x;
    const int gi = blockIdx.x * 512 + tid;        // 131072 threads x 4 elems

    f32x4 v = *(const f32x4*)(x + gi * 4);
    u16x4 h;
    h[0] = __builtin_bit_cast(unsigned short, (_Float16)v.x);
    h[1] = __builtin_bit_cast(unsigned short, (_Float16)v.y);
    h[2] = __builtin_bit_cast(unsigned short, (_Float16)v.z);
    h[3] = __builtin_bit_cast(unsigned short, (_Float16)v.w);
    *(u16x4*)(xb + gi * 4) = h;
    *(f32x4*)(out + gi * 4) = (f32x4){0.f, 0.f, 0.f, 0.f};

    if (blockIdx.x < SEQ) {   // t-row for s = blockIdx.x
        __shared__ float p[LORA_R][33];
        const int s = blockIdx.x;
        const int r = tid & 15, seg = tid >> 4;   // 32 segments x 256 cols
        const float* xr = x + s * IN_F + seg * 256;
        const float* ar = A + r * IN_F + seg * 256;
        float acc = 0.f;
        #pragma unroll 8
        for (int j = 0; j < 64; ++j) {
            f32x4 xv = *(const f32x4*)(xr + j * 4);
            f32x4 av = *(const f32x4*)(ar + j * 4);
            acc = fmaf(xv.x, av.x, acc);
            acc = fmaf(xv.y, av.y, acc);
            acc = fmaf(xv.z, av.z, acc);
            acc = fmaf(xv.w, av.w, acc);
        }
        p[r][seg] = acc;
        __syncthreads();
        if (tid < LORA_R) {
            float sum = 0.f;
            #pragma unroll
            for (int g = 0; g < 32; ++g) sum += p[tid][g];
            t[s * LORA_R + tid] = sum;
        }
    }
}

// ---- main: grid 512 = 128 ntiles(64 cols) x 4 kq; 512 thr = 8 waves ----
// waves: nh = w>>2 (32-col half), wkk = w&3 (k32 of BK=128). 16 iters of BK=128.
// LDS 78848 B: xs [2][64][136] f16 | wt [2][64][68] int | scs [64][36] f32
// -> 2 blocks/CU. Single barrier per iter, register prefetch d=1.
__global__ __launch_bounds__(512, 4) void k_main(
    const int* __restrict__ packed, const float* __restrict__ scales,
    const unsigned short* __restrict__ xb, const float* __restrict__ t,
    const float* __restrict__ B, float* __restrict__ out) {
    __shared__ char lds[78848];
    _Float16* xs = (_Float16*)lds;                     // 34816 B
    int*      wt = (int*)(lds + 34816);                // 34816 B
    float*    scs = (float*)(lds + 69632);             // 9216 B
    float*    accs = (float*)lds;                      // epilogue alias [4][64][33]

    const int tid = threadIdx.x;
    const int ntile = blockIdx.x >> 2, kq = blockIdx.x & 3;
    const int n0 = ntile * 64;
    const int w = tid >> 6, lane = tid & 63;
    const int nh = w >> 2, wkk = w & 3;
    const int q = lane >> 4, c16 = lane & 15;

    // stage scales: 64 rows x 32 kblocks for this K-quarter
    {
        int row = tid >> 3, g = tid & 7;
        f32x4 v = *(const f32x4*)(scales + (n0 + row) * 128 + kq * 32 + g * 4);
        *(f32x4*)(scs + row * 36 + g * 4) = v;
    }

    // staging coords: 64 rows x 8 segments per tile, 64 B/thread/iter total
    const int srow = tid >> 3, sseg = tid & 7;
    const unsigned short* xsrc = xb + srow * IN_F + kq * 2048 + sseg * 16;
    const int* wsrc = packed + (long)(n0 + srow) * 4096 + kq * 1024 + sseg * 8;

    f32x4 acc[8];   // [ct*4 + mt]
    #pragma unroll
    for (int i = 0; i < 8; ++i) acc[i] = (f32x4){0.f, 0.f, 0.f, 0.f};

    // prologue: stage iter 0 into buf 0
    {
        u16x8 xa = *(const u16x8*)xsrc;
        u16x8 xbv = *(const u16x8*)(xsrc + 8);
        i32x4 wa = *(const i32x4*)wsrc;
        i32x4 wb = *(const i32x4*)(wsrc + 4);
        *(u16x8*)(xs + srow * 136 + sseg * 16)     = xa;
        *(u16x8*)(xs + srow * 136 + sseg * 16 + 8) = xbv;
        *(i32x4*)(wt + srow * 68 + sseg * 8)       = wa;
        *(i32x4*)(wt + srow * 68 + sseg * 8 + 4)   = wb;
    }
    __syncthreads();

    const f16x2 c1032 = {(_Float16)1032.0f, (_Float16)1032.0f};

    for (int kt = 0; kt < 16; ++kt) {
        const int cur = kt & 1;
        u16x8 xa, xbv; i32x4 wa, wb;
        if (kt < 15) {   // prefetch next iter (in flight across compute)
            xa  = *(const u16x8*)(xsrc + (kt + 1) * 128);
            xbv = *(const u16x8*)(xsrc + (kt + 1) * 128 + 8);
            wa  = *(const i32x4*)(wsrc + (kt + 1) * 64);
            wb  = *(const i32x4*)(wsrc + (kt + 1) * 64 + 4);
        }

        // ---- compute current buffer: 8 MFMAs (2 ct x 4 mt) ----
        const _Float16* xbase = xs + cur * (64 * 136) + wkk * 32 + q * 8;
        f16x8 af0 = *(const f16x8*)(xbase + (0 * 16 + c16) * 136);
        f16x8 af1 = *(const f16x8*)(xbase + (1 * 16 + c16) * 136);
        f16x8 af2 = *(const f16x8*)(xbase + (2 * 16 + c16) * 136);
        f16x8 af3 = *(const f16x8*)(xbase + (3 * 16 + c16) * 136);
        #pragma unroll
        for (int ct = 0; ct < 2; ++ct) {
            const int row = nh * 32 + ct * 16 + c16;
            i32x4 pv = *(const i32x4*)(wt + cur * (64 * 68) + row * 68 + wkk * 16 + q * 4);
            float scf = scs[row * 36 + kt * 2 + (wkk >> 1)];
            _Float16 sch = (_Float16)scf;
            f16x2 sc2 = {sch, sch};
            f16x8 bf;
            #pragma unroll
            for (int m = 0; m < 4; ++m) {
                unsigned u = ((((unsigned)pv[m] << 12) | (unsigned)pv[m]) & 0x000F000Fu) | 0x64006400u;
                f16x2 hh = __builtin_bit_cast(f16x2, u);
                hh = (hh - c1032) * sc2;        // exact (q-8)*scale
                bf[2 * m] = hh.x;
                bf[2 * m + 1] = hh.y;
            }
            acc[ct * 4 + 0] = __builtin_amdgcn_mfma_f32_16x16x32_f16(af0, bf, acc[ct * 4 + 0], 0, 0, 0);
            acc[ct * 4 + 1] = __builtin_amdgcn_mfma_f32_16x16x32_f16(af1, bf, acc[ct * 4 + 1], 0, 0, 0);
            acc[ct * 4 + 2] = __builtin_amdgcn_mfma_f32_16x16x32_f16(af2, bf, acc[ct * 4 + 2], 0, 0, 0);
            acc[ct * 4 + 3] = __builtin_amdgcn_mfma_f32_16x16x32_f16(af3, bf, acc[ct * 4 + 3], 0, 0, 0);
        }
        // store prefetched data into the other buffer (WAR safe: its readers
        // finished before the barrier that ended iter kt-1)
        if (kt < 15) {
            *(u16x8*)(xs + (1 - cur) * (64 * 136) + srow * 136 + sseg * 16)     = xa;
            *(u16x8*)(xs + (1 - cur) * (64 * 136) + srow * 136 + sseg * 16 + 8) = xbv;
            *(i32x4*)(wt + (1 - cur) * (64 * 68) + srow * 68 + sseg * 8)        = wa;
            *(i32x4*)(wt + (1 - cur) * (64 * 68) + srow * 68 + sseg * 8 + 4)    = wb;
        }
        __syncthreads();
    }

    // ---- epilogue: two phases (nh=0,1), 4-way wkk reduce + LoRA (kq==0) + atomics ----
    #pragma unroll
    for (int ph = 0; ph < 2; ++ph) {
        if (nh == ph) {
            #pragma unroll
            for (int ct = 0; ct < 2; ++ct)
                #pragma unroll
                for (int mt = 0; mt < 4; ++mt)
                    #pragma unroll
                    for (int r = 0; r < 4; ++r)
                        accs[wkk * 2112 + (mt * 16 + q * 4 + r) * 33 + ct * 16 + c16] = acc[ct * 4 + mt][r];
        }
        __syncthreads();
        #pragma unroll
        for (int j = 0; j < 4; ++j) {
            int p = tid + j * 512;                 // 2048 outputs: m 0..63, c 0..31
            int m = p >> 5, c = p & 31;
            float v = accs[0 * 2112 + m * 33 + c] + accs[1 * 2112 + m * 33 + c] +
                      accs[2 * 2112 + m * 33 + c] + accs[3 * 2112 + m * 33 + c];
            int col = n0 + ph * 32 + c;
            if (kq == 0) {
                const float* tp = t + m * LORA_R;
                const float* bp = B + col * LORA_R;
                float lr = 0.f;
                #pragma unroll
                for (int r = 0; r < LORA_R; ++r) lr = fmaf(tp[r], bp[r], lr);
                v += 2.0f * lr;
            }
            unsafeAtomicAdd(&out[m * OUT_F + col], v);
        }
        __syncthreads();
    }
}

extern "C" void kernel_launch(void* const* d_in, const int* in_sizes, int n_in,
                              void* d_out, int out_size, void* d_ws, size_t ws_size,
                              hipStream_t stream) {
    const float* x      = (const float*)d_in[0];
    const int* packed   = (const int*)d_in[1];
    const float* scales = (const float*)d_in[2];
    const float* lora_A = (const float*)d_in[3];
    const float* lora_B = (const float*)d_in[4];
    float* out = (float*)d_out;

    unsigned short* xb = (unsigned short*)d_ws;                 // 1 MiB fp16 x
    float* t = (float*)((char*)d_ws + (size_t)SEQ * IN_F * 2);  // 4 KiB

    k_prep<<<256, 512, 0, stream>>>(x, lora_A, xb, t, out);
    k_main<<<512, 512, 0, stream>>>(packed, scales, xb, t, lora_B, out);
}